// Round 4
// baseline (705.610 us; speedup 1.0000x reference)
//
#include <hip/hip_runtime.h>

#define B_  64
#define C_  256
#define CS  64
#define NC  8
#define HW  4096
#define BC  16384   // B_*C_

// ALL tensors fp32 (x, w1, b1, w2, b2, act_range fp32; sample_cluster int32; out fp32).

// ---------------- Kernel 1: per-(b,c) plane sum/min/max over HW ----------------
__global__ __launch_bounds__(256) void k_reduce(const float* __restrict__ x,
    float* __restrict__ sumb, float* __restrict__ minb, float* __restrict__ maxb){
  int p = blockIdx.x;
  int t = threadIdx.x;
  const float4* base = (const float4*)(x + (size_t)p * HW);
  float s = 0.f, mn = INFINITY, mx = -INFINITY;
  #pragma unroll
  for (int k = 0; k < 4; k++){
    float4 v = base[t + 256 * k];
    s += (v.x + v.y) + (v.z + v.w);
    mn = fminf(mn, fminf(fminf(v.x, v.y), fminf(v.z, v.w)));
    mx = fmaxf(mx, fmaxf(fmaxf(v.x, v.y), fmaxf(v.z, v.w)));
  }
  #pragma unroll
  for (int off = 1; off < 64; off <<= 1){
    s  += __shfl_xor(s, off, 64);
    mn  = fminf(mn, __shfl_xor(mn, off, 64));
    mx  = fmaxf(mx, __shfl_xor(mx, off, 64));
  }
  __shared__ float ls[4], lmn[4], lmx[4];
  int w = t >> 6;
  if ((t & 63) == 0){ ls[w] = s; lmn[w] = mn; lmx[w] = mx; }
  __syncthreads();
  if (t == 0){
    sumb[p] = ls[0] + ls[1] + ls[2] + ls[3];
    minb[p] = fminf(fminf(lmn[0], lmn[1]), fminf(lmn[2], lmn[3]));
    maxb[p] = fmaxf(fmaxf(lmx[0], lmx[1]), fmaxf(lmx[2], lmx[3]));
  }
}

// ---------------- Kernel 2: MLP + hardsigmoid + cluster EMA + quant params ----------------
__global__ __launch_bounds__(1024) void k_small(
    const float* __restrict__ sumb, const float* __restrict__ minb, const float* __restrict__ maxb,
    const float* __restrict__ w1, const float* __restrict__ b1,
    const float* __restrict__ w2, const float* __restrict__ b2,
    const float* __restrict__ act_range, const int* __restrict__ clus,
    float* __restrict__ scaleb, float* __restrict__ ssb, float* __restrict__ zzb){
  __shared__ float s_h[B_ * CS];
  __shared__ float s_smin[B_], s_smax[B_];
  __shared__ float s_s[NC], s_z[NC];
  int tid = threadIdx.x;

  // h[b][s] = relu( (sum_c sum_hw x * w1[s][c]) / 4096 + b1[s] )  (/4096 exact pow2 fold)
  for (int o = tid; o < B_ * CS; o += 1024){
    int b = o >> 6, s = o & 63;
    const float4* pc = (const float4*)(sumb + b * C_);
    const float4* wr = (const float4*)(w1 + s * C_);
    float acc = 0.f;
    #pragma unroll 8
    for (int i = 0; i < 64; i++){
      float4 p = pc[i], w = wr[i];
      acc += p.x*w.x + p.y*w.y + p.z*w.z + p.w*w.w;
    }
    float hv = acc * (1.0f / 4096.0f) + b1[s];
    s_h[o] = fmaxf(hv, 0.f);
  }
  __syncthreads();

  // scale[b][c] = hardsigmoid( sum_s h[b][s] * w2[c][s] + b2[c] )
  for (int o = tid; o < BC; o += 1024){
    int b = o >> 8, c = o & 255;
    const float4* wr = (const float4*)(w2 + c * CS);
    const float4* hh = (const float4*)(s_h + b * CS);
    float acc = 0.f;
    #pragma unroll
    for (int i = 0; i < 16; i++){
      float4 w = wr[i], h = hh[i];
      acc += h.x*w.x + h.y*w.y + h.z*w.z + h.w*w.w;
    }
    float v = acc + b2[c];
    float sc = fminf(fmaxf(v * (1.0f / 6.0f) + 0.5f, 0.f), 1.f);
    scaleb[o] = sc;
  }
  __syncthreads();

  // per-sample min/max of out = scale*x: scale>=0, fp32 mul monotone -> exact
  if (tid < B_){
    float mn = INFINITY, mx = -INFINITY;
    for (int c = 0; c < C_; c++){
      float sc = scaleb[tid * C_ + c];
      mn = fminf(mn, sc * minb[tid * C_ + c]);
      mx = fmaxf(mx, sc * maxb[tid * C_ + c]);
    }
    s_smin[tid] = mn; s_smax[tid] = mx;
  }
  __syncthreads();

  // per-cluster segment min/max (+-inf identity like jax.ops.segment_*), EMA, s/z
  if (tid < NC){
    float cm = INFINITY, cM = -INFINITY;
    for (int b = 0; b < B_; b++){
      if (clus[b] == tid){ cm = fminf(cm, s_smin[b]); cM = fmaxf(cM, s_smax[b]); }
    }
    float nmin = act_range[2*tid]     * 0.995f + cm * 0.005f;
    float nmax = act_range[2*tid + 1] * 0.995f + cM * 0.005f;
    float sv = (nmax - nmin) / 255.0f;
    float zv = -rintf(nmin / sv);           // rintf = round-half-even = jnp.round
    s_s[tid] = sv; s_z[tid] = zv;
  }
  __syncthreads();

  if (tid < B_){
    int k = clus[tid];
    ssb[tid] = s_s[k];
    zzb[tid] = s_z[k];
  }
}

// ---------------- Kernel 3: elementwise fake-quant (fp32 in -> fp32 out) ----------------
__global__ __launch_bounds__(256) void k_quant(const float* __restrict__ x,
    const float* __restrict__ scaleb, const float* __restrict__ ssb, const float* __restrict__ zzb,
    float* __restrict__ out){
  int p = blockIdx.x;
  int b = p >> 8;
  float sc = scaleb[p];
  float ss = ssb[b];
  float zz = zzb[b];
  const float4* xin = (const float4*)(x + (size_t)p * HW);
  float4*       oq  = (float4*)(out + (size_t)p * HW);
  int t = threadIdx.x;
  #pragma unroll
  for (int k = 0; k < 4; k++){
    float4 v = xin[t + 256 * k];
    float in[4] = {v.x, v.y, v.z, v.w};
    float r[4];
    #pragma unroll
    for (int i = 0; i < 4; i++){
      float o = sc * in[i];
      float q = fminf(fmaxf(rintf(o / ss + zz), 0.f), 255.f);
      float f = (q - zz) * ss;
      r[i] = o + (f - o);   // reproduce ref's out + (fq - out) fp ordering
    }
    float4 res; res.x = r[0]; res.y = r[1]; res.z = r[2]; res.w = r[3];
    oq[t + 256 * k] = res;
  }
}

extern "C" void kernel_launch(void* const* d_in, const int* in_sizes, int n_in,
                              void* d_out, int out_size, void* d_ws, size_t ws_size,
                              hipStream_t stream) {
  const float* x  = (const float*)d_in[0];
  const float* w1 = (const float*)d_in[1];
  const float* b1 = (const float*)d_in[2];
  const float* w2 = (const float*)d_in[3];
  const float* b2 = (const float*)d_in[4];
  const float* ar = (const float*)d_in[5];
  const int* clus = (const int*)d_in[6];
  float* out = (float*)d_out;

  float* ws    = (float*)d_ws;
  float* sumb  = ws;            // 16384
  float* minb  = ws + BC;       // 16384
  float* maxb  = ws + 2 * BC;   // 16384
  float* scaleb= ws + 3 * BC;   // 16384
  float* ssb   = ws + 4 * BC;   // 64
  float* zzb   = ssb + B_;      // 64

  hipLaunchKernelGGL(k_reduce, dim3(BC), dim3(256), 0, stream, x, sumb, minb, maxb);
  hipLaunchKernelGGL(k_small, dim3(1), dim3(1024), 0, stream,
                     sumb, minb, maxb, w1, b1, w2, b2, ar, clus, scaleb, ssb, zzb);
  hipLaunchKernelGGL(k_quant, dim3(BC), dim3(256), 0, stream, x, scaleb, ssb, zzb, out);
}

// Round 5
// 509.937 us; speedup vs baseline: 1.3837x; 1.3837x over previous
//
#include <hip/hip_runtime.h>

#define B_  64
#define C_  256
#define CS  64
#define NC  8
#define HW  4096
#define BC  16384   // B_*C_

// ALL tensors fp32 (x, w1, b1, w2, b2, act_range fp32; sample_cluster int32; out fp32).

// ---------------- Kernel 1: per-(b,c) plane sum/min/max over HW ----------------
__global__ __launch_bounds__(256) void k_reduce(const float* __restrict__ x,
    float* __restrict__ sumb, float* __restrict__ minb, float* __restrict__ maxb){
  int p = blockIdx.x;
  int t = threadIdx.x;
  const float4* base = (const float4*)(x + (size_t)p * HW);
  float s = 0.f, mn = INFINITY, mx = -INFINITY;
  #pragma unroll
  for (int k = 0; k < 4; k++){
    float4 v = base[t + 256 * k];
    s += (v.x + v.y) + (v.z + v.w);
    mn = fminf(mn, fminf(fminf(v.x, v.y), fminf(v.z, v.w)));
    mx = fmaxf(mx, fmaxf(fmaxf(v.x, v.y), fmaxf(v.z, v.w)));
  }
  #pragma unroll
  for (int off = 1; off < 64; off <<= 1){
    s  += __shfl_xor(s, off, 64);
    mn  = fminf(mn, __shfl_xor(mn, off, 64));
    mx  = fmaxf(mx, __shfl_xor(mx, off, 64));
  }
  __shared__ float ls[4], lmn[4], lmx[4];
  int w = t >> 6;
  if ((t & 63) == 0){ ls[w] = s; lmn[w] = mn; lmx[w] = mx; }
  __syncthreads();
  if (t == 0){
    sumb[p] = ls[0] + ls[1] + ls[2] + ls[3];
    minb[p] = fminf(fminf(lmn[0], lmn[1]), fminf(lmn[2], lmn[3]));
    maxb[p] = fmaxf(fmaxf(lmx[0], lmx[1]), fmaxf(lmx[2], lmx[3]));
  }
}

// ---------------- Kernel 2a: per-sample MLP + hardsigmoid + sample min/max ----------------
// grid = 64 blocks (one per batch sample), 256 threads (one per channel c)
__global__ __launch_bounds__(256) void k_mlp(
    const float* __restrict__ sumb, const float* __restrict__ minb, const float* __restrict__ maxb,
    const float* __restrict__ w1, const float* __restrict__ b1,
    const float* __restrict__ w2, const float* __restrict__ b2,
    float* __restrict__ scaleb, float* __restrict__ sminb, float* __restrict__ smaxb){
  int b = blockIdx.x;
  int t = threadIdx.x;
  __shared__ float s_pool[C_];
  __shared__ float s_h[CS];
  __shared__ float lmn[4], lmx[4];

  s_pool[t] = sumb[b * C_ + t] * (1.0f / 4096.0f);   // pooled = sum/4096 (exact pow2)
  __syncthreads();

  if (t < CS){
    const float4* pw = (const float4*)(w1 + t * C_);
    const float4* pp = (const float4*)s_pool;
    float acc = 0.f;
    #pragma unroll
    for (int i = 0; i < 64; i++){
      float4 w = pw[i], p = pp[i];
      acc += p.x*w.x + p.y*w.y + p.z*w.z + p.w*w.w;
    }
    s_h[t] = fmaxf(acc + b1[t], 0.f);
  }
  __syncthreads();

  // channel c = t: scale = hardsigmoid(dot(h, w2[c]) + b2[c])
  const float4* pw2 = (const float4*)(w2 + t * CS);
  const float4* ph  = (const float4*)s_h;
  float acc = 0.f;
  #pragma unroll
  for (int i = 0; i < 16; i++){
    float4 w = pw2[i], h = ph[i];
    acc += h.x*w.x + h.y*w.y + h.z*w.z + h.w*w.w;
  }
  float v = acc + b2[t];
  float sc = fminf(fmaxf(v * (1.0f / 6.0f) + 0.5f, 0.f), 1.f);
  scaleb[b * C_ + t] = sc;

  // per-sample min/max of out = scale*x: scale>=0, fp32 mul monotone -> exact
  float mn = sc * minb[b * C_ + t];
  float mx = sc * maxb[b * C_ + t];
  #pragma unroll
  for (int off = 1; off < 64; off <<= 1){
    mn = fminf(mn, __shfl_xor(mn, off, 64));
    mx = fmaxf(mx, __shfl_xor(mx, off, 64));
  }
  int w = t >> 6;
  if ((t & 63) == 0){ lmn[w] = mn; lmx[w] = mx; }
  __syncthreads();
  if (t == 0){
    sminb[b] = fminf(fminf(lmn[0], lmn[1]), fminf(lmn[2], lmn[3]));
    smaxb[b] = fmaxf(fmaxf(lmx[0], lmx[1]), fmaxf(lmx[2], lmx[3]));
  }
}

// ---------------- Kernel 2b: cluster segment min/max + EMA + quant params ----------------
__global__ __launch_bounds__(64) void k_cluster(
    const float* __restrict__ sminb, const float* __restrict__ smaxb,
    const float* __restrict__ act_range, const int* __restrict__ clus,
    float* __restrict__ ssb, float* __restrict__ zzb){
  __shared__ float s_s[NC], s_z[NC];
  int t = threadIdx.x;
  if (t < NC){
    float cm = INFINITY, cM = -INFINITY;
    for (int b = 0; b < B_; b++){
      if (clus[b] == t){ cm = fminf(cm, sminb[b]); cM = fmaxf(cM, smaxb[b]); }
    }
    float nmin = act_range[2*t]     * 0.995f + cm * 0.005f;
    float nmax = act_range[2*t + 1] * 0.995f + cM * 0.005f;
    float sv = (nmax - nmin) / 255.0f;
    s_s[t] = sv;
    s_z[t] = -rintf(nmin / sv);          // rintf = round-half-even = jnp.round
  }
  __syncthreads();
  int k = clus[t];
  ssb[t] = s_s[k];
  zzb[t] = s_z[k];
}

// ---------------- Kernel 3: elementwise fake-quant (fp32 in -> fp32 out) ----------------
__global__ __launch_bounds__(256) void k_quant(const float* __restrict__ x,
    const float* __restrict__ scaleb, const float* __restrict__ ssb, const float* __restrict__ zzb,
    float* __restrict__ out){
  int p = blockIdx.x;
  int b = p >> 8;
  float sc = scaleb[p];
  float ss = ssb[b];
  float zz = zzb[b];
  const float4* xin = (const float4*)(x + (size_t)p * HW);
  float4*       oq  = (float4*)(out + (size_t)p * HW);
  int t = threadIdx.x;
  #pragma unroll
  for (int k = 0; k < 4; k++){
    float4 v = xin[t + 256 * k];
    float in[4] = {v.x, v.y, v.z, v.w};
    float r[4];
    #pragma unroll
    for (int i = 0; i < 4; i++){
      float o = sc * in[i];
      float q = fminf(fmaxf(rintf(o / ss + zz), 0.f), 255.f);
      float f = (q - zz) * ss;
      r[i] = o + (f - o);   // reproduce ref's out + (fq - out) fp ordering
    }
    float4 res; res.x = r[0]; res.y = r[1]; res.z = r[2]; res.w = r[3];
    oq[t + 256 * k] = res;
  }
}

extern "C" void kernel_launch(void* const* d_in, const int* in_sizes, int n_in,
                              void* d_out, int out_size, void* d_ws, size_t ws_size,
                              hipStream_t stream) {
  const float* x  = (const float*)d_in[0];
  const float* w1 = (const float*)d_in[1];
  const float* b1 = (const float*)d_in[2];
  const float* w2 = (const float*)d_in[3];
  const float* b2 = (const float*)d_in[4];
  const float* ar = (const float*)d_in[5];
  const int* clus = (const int*)d_in[6];
  float* out = (float*)d_out;

  float* ws    = (float*)d_ws;
  float* sumb  = ws;            // 16384
  float* minb  = ws + BC;       // 16384
  float* maxb  = ws + 2 * BC;   // 16384
  float* scaleb= ws + 3 * BC;   // 16384
  float* ssb   = ws + 4 * BC;        // 64
  float* zzb   = ssb + B_;           // 64
  float* sminb = zzb + B_;           // 64
  float* smaxb = sminb + B_;         // 64

  hipLaunchKernelGGL(k_reduce, dim3(BC), dim3(256), 0, stream, x, sumb, minb, maxb);
  hipLaunchKernelGGL(k_mlp, dim3(B_), dim3(256), 0, stream,
                     sumb, minb, maxb, w1, b1, w2, b2, scaleb, sminb, smaxb);
  hipLaunchKernelGGL(k_cluster, dim3(1), dim3(64), 0, stream,
                     sminb, smaxb, ar, clus, ssb, zzb);
  hipLaunchKernelGGL(k_quant, dim3(BC), dim3(256), 0, stream, x, scaleb, ssb, zzb, out);
}